// Round 2
// baseline (493.438 us; speedup 1.0000x reference)
//
#include <hip/hip_runtime.h>

// FocalLoss (RetinaNet) on MI355X.
// Stage A: per-anchor IoU/assignment -> meta[B][A], num_pos[B], reg_sum[B]
// Stage B: coalesced float4 sweep of classifications -> cls_sum[B]
// Stage C: finalize means -> d_out[0..1]

__global__ __launch_bounds__(256) void stageA_kernel(
    const float* __restrict__ anchors,      // [A,4]
    const float* __restrict__ regressions,  // [B,A,4]
    const float* __restrict__ annotations,  // [B,M,5]
    int* __restrict__ meta,                 // [B,A]
    float* __restrict__ reg_sum,            // [B]
    unsigned int* __restrict__ npos,        // [B]
    int A, int M)
{
    const int b = blockIdx.y;
    const int a = blockIdx.x * blockDim.x + threadIdx.x;

    __shared__ float ann[512];              // up to 102 GTs * 5; M=32 -> 160 floats used
    const int nl = M * 5;
    for (int i = threadIdx.x; i < nl; i += blockDim.x)
        ann[i] = annotations[b * nl + i];
    __syncthreads();

    float regl = 0.0f;
    float posf = 0.0f;

    if (a < A) {
        const float4 ab = *reinterpret_cast<const float4*>(anchors + (size_t)a * 4);
        const float aw = ab.z - ab.x, ah = ab.w - ab.y;
        const float areaA = aw * ah;

        float best = -3.0e38f;
        int arg = 0;
        for (int m = 0; m < M; ++m) {
            const float bx1 = ann[m * 5 + 0], by1 = ann[m * 5 + 1];
            const float bx2 = ann[m * 5 + 2], by2 = ann[m * 5 + 3];
            const float lb  = ann[m * 5 + 4];
            float iw = fmaxf(fminf(ab.z, bx2) - fmaxf(ab.x, bx1), 0.0f);
            float ih = fmaxf(fminf(ab.w, by2) - fmaxf(ab.y, by1), 0.0f);
            float inter = iw * ih;
            float ua = fmaxf(areaA + (bx2 - bx1) * (by2 - by1) - inter, 1e-8f);
            float iou = inter / ua;
            iou = (lb != -1.0f) ? iou : -1.0f;   // mask padded GTs
            if (iou > best) { best = iou; arg = m; }  // strict > == argmax first-occurrence
        }

        int mv;
        if (best >= 0.5f) {
            mv = (int)ann[arg * 5 + 4];       // positive: class label
            posf = 1.0f;
            // regression loss (positives only)
            const float4 rg = *reinterpret_cast<const float4*>(
                regressions + ((size_t)b * A + a) * 4);
            const float gx1 = ann[arg * 5 + 0], gy1 = ann[arg * 5 + 1];
            const float gx2 = ann[arg * 5 + 2], gy2 = ann[arg * 5 + 3];
            const float acx = ab.x + 0.5f * aw, acy = ab.y + 0.5f * ah;
            const float gwr = gx2 - gx1, ghr = gy2 - gy1;
            const float gcx = gx1 + 0.5f * gwr, gcy = gy1 + 0.5f * ghr;
            const float gw = fmaxf(gwr, 1.0f), gh = fmaxf(ghr, 1.0f);
            const float t0 = ((gcx - acx) / aw) / 0.1f;
            const float t1 = ((gcy - acy) / ah) / 0.1f;
            const float t2 = logf(gw / aw) / 0.2f;
            const float t3 = logf(gh / ah) / 0.2f;
            const float d0 = fabsf(t0 - rg.x), d1 = fabsf(t1 - rg.y);
            const float d2 = fabsf(t2 - rg.z), d3 = fabsf(t3 - rg.w);
            const float th = 1.0f / 9.0f, c = 0.5f / 9.0f;
            regl  = (d0 <= th) ? 4.5f * d0 * d0 : d0 - c;
            regl += (d1 <= th) ? 4.5f * d1 * d1 : d1 - c;
            regl += (d2 <= th) ? 4.5f * d2 * d2 : d2 - c;
            regl += (d3 <= th) ? 4.5f * d3 * d3 : d3 - c;
        } else if (best < 0.4f) {
            mv = -1;                          // negative: t = 0 for all classes
        } else {
            mv = -2;                          // ignore band [0.4, 0.5)
        }
        meta[(size_t)b * A + a] = mv;
    }

    // block reduction: regl and posf
    #pragma unroll
    for (int off = 32; off > 0; off >>= 1) {
        regl += __shfl_down(regl, off, 64);
        posf += __shfl_down(posf, off, 64);
    }
    __shared__ float wred[8];
    const int wave = threadIdx.x >> 6;
    const int lane = threadIdx.x & 63;
    if (lane == 0) { wred[wave] = regl; wred[4 + wave] = posf; }
    __syncthreads();
    if (threadIdx.x == 0) {
        const float r = wred[0] + wred[1] + wred[2] + wred[3];
        const float p = wred[4] + wred[5] + wred[6] + wred[7];
        if (r != 0.0f) atomicAdd(&reg_sum[b], r);
        if (p != 0.0f) atomicAdd(&npos[b], (unsigned int)p);
    }
}

// KV = K/4 as a compile-time constant so v/KV, v%KV become magic-mul.
template <int KV>
__global__ __launch_bounds__(256) void stageB_kernel(
    const float* __restrict__ cls,   // [B,A,K]
    const int* __restrict__ meta,    // [B,A]
    float* __restrict__ cls_sum,     // [B]
    int A)
{
    const int b = blockIdx.y;
    const size_t nvec = (size_t)A * KV;
    const float4* __restrict__ base =
        reinterpret_cast<const float4*>(cls + (size_t)b * A * (KV * 4));
    const int* __restrict__ mbase = meta + (size_t)b * A;

    float acc = 0.0f;
    const unsigned int stride = gridDim.x * blockDim.x;
    for (size_t v = (size_t)blockIdx.x * blockDim.x + threadIdx.x; v < nvec; v += stride) {
        const float4 c4 = base[v];
        const unsigned int vu = (unsigned int)v;
        const int a = (int)(vu / KV);
        const int kbase = (int)(vu % KV) * 4;
        const int mv = mbase[a];
        if (mv != -2) {
            const float cv[4] = {c4.x, c4.y, c4.z, c4.w};
            #pragma unroll
            for (int j = 0; j < 4; ++j) {
                const float cc = fminf(fmaxf(cv[j], 1e-4f), 0.9999f);
                const bool t1 = (mv == kbase + j);      // one-hot hit (false for mv==-1)
                const float x = t1 ? cc : (1.0f - cc);  // arg of log
                const float w = t1 ? 0.25f * (1.0f - cc) * (1.0f - cc)
                                   : 0.75f * cc * cc;
                acc += w * (-__logf(x));
            }
        }
    }

    #pragma unroll
    for (int off = 32; off > 0; off >>= 1)
        acc += __shfl_down(acc, off, 64);
    __shared__ float wred[4];
    const int wave = threadIdx.x >> 6;
    const int lane = threadIdx.x & 63;
    if (lane == 0) wred[wave] = acc;
    __syncthreads();
    if (threadIdx.x == 0)
        atomicAdd(&cls_sum[b], wred[0] + wred[1] + wred[2] + wred[3]);
}

// generic fallback (runtime K)
__global__ __launch_bounds__(256) void stageB_generic(
    const float* __restrict__ cls, const int* __restrict__ meta,
    float* __restrict__ cls_sum, int A, int K)
{
    const int b = blockIdx.y;
    const int kv = K / 4;
    const size_t nvec = (size_t)A * kv;
    const float4* __restrict__ base =
        reinterpret_cast<const float4*>(cls + (size_t)b * A * K);
    const int* __restrict__ mbase = meta + (size_t)b * A;

    float acc = 0.0f;
    const unsigned int stride = gridDim.x * blockDim.x;
    for (size_t v = (size_t)blockIdx.x * blockDim.x + threadIdx.x; v < nvec; v += stride) {
        const float4 c4 = base[v];
        const int a = (int)(v / kv);
        const int kbase = (int)(v % kv) * 4;
        const int mv = mbase[a];
        if (mv != -2) {
            const float cv[4] = {c4.x, c4.y, c4.z, c4.w};
            #pragma unroll
            for (int j = 0; j < 4; ++j) {
                const float cc = fminf(fmaxf(cv[j], 1e-4f), 0.9999f);
                const bool t1 = (mv == kbase + j);
                const float x = t1 ? cc : (1.0f - cc);
                const float w = t1 ? 0.25f * (1.0f - cc) * (1.0f - cc)
                                   : 0.75f * cc * cc;
                acc += w * (-__logf(x));
            }
        }
    }

    #pragma unroll
    for (int off = 32; off > 0; off >>= 1)
        acc += __shfl_down(acc, off, 64);
    __shared__ float wred[4];
    const int wave = threadIdx.x >> 6;
    const int lane = threadIdx.x & 63;
    if (lane == 0) wred[wave] = acc;
    __syncthreads();
    if (threadIdx.x == 0)
        atomicAdd(&cls_sum[b], wred[0] + wred[1] + wred[2] + wred[3]);
}

__global__ void stageC_kernel(
    const float* __restrict__ annotations,  // [B,M,5]
    const float* __restrict__ cls_sum,
    const float* __restrict__ reg_sum,
    const unsigned int* __restrict__ npos,
    float* __restrict__ out,
    int B, int M)
{
    if (threadIdx.x == 0 && blockIdx.x == 0) {
        float cm = 0.0f, rm = 0.0f;
        for (int b = 0; b < B; ++b) {
            bool hv = false;
            for (int m = 0; m < M; ++m)
                if (annotations[(b * M + m) * 5 + 4] != -1.0f) { hv = true; break; }
            const float np = (float)npos[b];
            float ct = cls_sum[b] / fmaxf(np, 1.0f);
            if (!hv) ct = 0.0f;
            const float rt = (np > 0.0f) ? reg_sum[b] / fmaxf(np * 4.0f, 1.0f) : 0.0f;
            cm += ct;
            rm += rt;
        }
        out[0] = cm / (float)B;
        out[1] = rm / (float)B;
    }
}

extern "C" void kernel_launch(void* const* d_in, const int* in_sizes, int n_in,
                              void* d_out, int out_size, void* d_ws, size_t ws_size,
                              hipStream_t stream) {
    const float* cls = (const float*)d_in[0];   // [B,A,K]
    const float* reg = (const float*)d_in[1];   // [B,A,4]
    const float* anc = (const float*)d_in[2];   // [1,A,4]
    const float* ann = (const float*)d_in[3];   // [B,M,5]

    const int A = in_sizes[2] / 4;
    const int B = in_sizes[1] / (A * 4);
    const int M = in_sizes[3] / (B * 5);
    const int K = in_sizes[0] / (B * A);

    float* out = (float*)d_out;
    // workspace: [0,256) bytes of accumulators, then meta[B][A] ints
    float* cls_sum = (float*)d_ws;              // B floats
    float* reg_sum = cls_sum + B;               // B floats
    unsigned int* npos = (unsigned int*)(reg_sum + B);  // B uints
    int* meta = (int*)((char*)d_ws + 256);      // B*A ints (~3.84 MB)

    hipMemsetAsync(d_ws, 0, 256, stream);

    dim3 ga((A + 255) / 256, B);
    stageA_kernel<<<ga, 256, 0, stream>>>(anc, reg, ann, meta, reg_sum, npos, A, M);

    dim3 gb(512, B);
    if (K == 80) {
        stageB_kernel<20><<<gb, 256, 0, stream>>>(cls, meta, cls_sum, A);
    } else {
        stageB_generic<<<gb, 256, 0, stream>>>(cls, meta, cls_sum, A, K);
    }

    stageC_kernel<<<1, 64, 0, stream>>>(ann, cls_sum, reg_sum, npos, out, B, M);
}

// Round 4
// 434.277 us; speedup vs baseline: 1.1362x; 1.1362x over previous
//
#include <hip/hip_runtime.h>

// FocalLoss (RetinaNet) on MI355X — fused 2-kernel design, no memset, no atomics.
//
// Kernel 1 (fused): each block owns CHUNK=256 anchors of one image.
//   Phase 1: per-anchor IoU/assignment vs M GT boxes (from LDS) -> meta in LDS,
//            smooth-L1 regression partial + positive count (registers).
//   Phase 2: coalesced float4 sweep of this chunk's [256 x K] classification
//            slab computing the focal-loss partial.
//   Block-reduce -> per-block partials (pcls/preg/ppos). Every slot written.
// Kernel 2: single block reduces partials per image, applies normalization,
//   means over images, writes out[0..1].

#define CHUNK 256

template <int KV>   // K/4 as compile-time constant (magic-mul div/mod)
__global__ __launch_bounds__(256) void fused_kernel(
    const float* __restrict__ cls,       // [B,A,K]
    const float* __restrict__ regr,      // [B,A,4]
    const float* __restrict__ anchors,   // [A,4]
    const float* __restrict__ ann_g,     // [B,M,5]
    float* __restrict__ pcls,            // [B,nblk]
    float* __restrict__ preg,            // [B,nblk]
    float* __restrict__ ppos,            // [B,nblk]
    int A, int M)
{
    const int b   = blockIdx.y;
    const int blk = blockIdx.x;
    const int a0  = blk * CHUNK;
    const int tid = threadIdx.x;

    __shared__ float ann[512];          // M*5 floats (M<=102)
    __shared__ int   smeta[CHUNK];
    const int nl = M * 5;
    for (int i = tid; i < nl; i += 256) ann[i] = ann_g[b * nl + i];
    __syncthreads();

    // ---- Phase 1: assignment for anchor a0+tid ----
    float regl = 0.0f, posf = 0.0f;
    int mv = -2;                        // pad anchors: treated as "ignore"
    const int a = a0 + tid;
    if (a < A) {
        const float4 ab = *reinterpret_cast<const float4*>(anchors + (size_t)a * 4);
        const float aw = ab.z - ab.x, ah = ab.w - ab.y;
        const float areaA = aw * ah;

        float best = -3.0e38f;
        int arg = 0;
        for (int m = 0; m < M; ++m) {
            const float bx1 = ann[m * 5 + 0], by1 = ann[m * 5 + 1];
            const float bx2 = ann[m * 5 + 2], by2 = ann[m * 5 + 3];
            const float lb  = ann[m * 5 + 4];
            float iw = fmaxf(fminf(ab.z, bx2) - fmaxf(ab.x, bx1), 0.0f);
            float ih = fmaxf(fminf(ab.w, by2) - fmaxf(ab.y, by1), 0.0f);
            float inter = iw * ih;
            float ua = fmaxf(areaA + (bx2 - bx1) * (by2 - by1) - inter, 1e-8f);
            float iou = inter / ua;
            iou = (lb != -1.0f) ? iou : -1.0f;        // mask padded GTs
            if (iou > best) { best = iou; arg = m; }  // strict > == first-occurrence argmax
        }

        if (best >= 0.5f) {
            mv = (int)ann[arg * 5 + 4];               // positive: class label
            posf = 1.0f;
            const float4 rg = *reinterpret_cast<const float4*>(
                regr + ((size_t)b * A + a) * 4);
            const float gx1 = ann[arg * 5 + 0], gy1 = ann[arg * 5 + 1];
            const float gx2 = ann[arg * 5 + 2], gy2 = ann[arg * 5 + 3];
            const float acx = ab.x + 0.5f * aw, acy = ab.y + 0.5f * ah;
            const float gwr = gx2 - gx1, ghr = gy2 - gy1;
            const float gcx = gx1 + 0.5f * gwr, gcy = gy1 + 0.5f * ghr;
            const float gw = fmaxf(gwr, 1.0f), gh = fmaxf(ghr, 1.0f);
            const float t0 = ((gcx - acx) / aw) / 0.1f;
            const float t1 = ((gcy - acy) / ah) / 0.1f;
            const float t2 = logf(gw / aw) / 0.2f;
            const float t3 = logf(gh / ah) / 0.2f;
            const float d0 = fabsf(t0 - rg.x), d1 = fabsf(t1 - rg.y);
            const float d2 = fabsf(t2 - rg.z), d3 = fabsf(t3 - rg.w);
            const float th = 1.0f / 9.0f, c = 0.5f / 9.0f;
            regl  = (d0 <= th) ? 4.5f * d0 * d0 : d0 - c;
            regl += (d1 <= th) ? 4.5f * d1 * d1 : d1 - c;
            regl += (d2 <= th) ? 4.5f * d2 * d2 : d2 - c;
            regl += (d3 <= th) ? 4.5f * d3 * d3 : d3 - c;
        } else if (best < 0.4f) {
            mv = -1;                                  // negative: t = 0 row
        }                                             // else ignore band -> -2
    }
    smeta[tid] = mv;
    __syncthreads();

    // ---- Phase 2: focal loss over this chunk's classification slab ----
    const int span = min(CHUNK, A - a0);
    const int nv = span * KV;
    const float4* __restrict__ base =
        reinterpret_cast<const float4*>(cls + ((size_t)b * A + a0) * (KV * 4));

    float acc = 0.0f;
    for (int t = tid; t < nv; t += 256) {
        const float4 c4 = base[t];
        const int la    = t / KV;          // local anchor (magic-mul)
        const int kbase = (t % KV) * 4;
        const int m2 = smeta[la];
        if (m2 != -2) {
            const float cv[4] = {c4.x, c4.y, c4.z, c4.w};
            #pragma unroll
            for (int j = 0; j < 4; ++j) {
                const float cc = fminf(fmaxf(cv[j], 1e-4f), 0.9999f);
                const bool t1 = (m2 == kbase + j);      // one-hot hit (false for -1)
                const float x = t1 ? cc : (1.0f - cc);
                const float w = t1 ? 0.25f * (1.0f - cc) * (1.0f - cc)
                                   : 0.75f * cc * cc;
                acc += w * (-__logf(x));
            }
        }
    }

    // ---- block reduction of acc / regl / posf ----
    #pragma unroll
    for (int off = 32; off > 0; off >>= 1) {
        acc  += __shfl_down(acc,  off, 64);
        regl += __shfl_down(regl, off, 64);
        posf += __shfl_down(posf, off, 64);
    }
    __shared__ float wred[12];
    const int wave = tid >> 6, lane = tid & 63;
    if (lane == 0) { wred[wave] = acc; wred[4 + wave] = regl; wred[8 + wave] = posf; }
    __syncthreads();
    if (tid == 0) {
        const size_t o = (size_t)b * gridDim.x + blk;
        pcls[o] = wred[0] + wred[1] + wred[2] + wred[3];
        preg[o] = wred[4] + wred[5] + wred[6] + wred[7];
        ppos[o] = wred[8] + wred[9] + wred[10] + wred[11];
    }
}

// runtime-KV fallback (identical structure)
__global__ __launch_bounds__(256) void fused_generic(
    const float* __restrict__ cls, const float* __restrict__ regr,
    const float* __restrict__ anchors, const float* __restrict__ ann_g,
    float* __restrict__ pcls, float* __restrict__ preg, float* __restrict__ ppos,
    int A, int M, int KV)
{
    const int b   = blockIdx.y;
    const int blk = blockIdx.x;
    const int a0  = blk * CHUNK;
    const int tid = threadIdx.x;

    __shared__ float ann[512];
    __shared__ int   smeta[CHUNK];
    const int nl = M * 5;
    for (int i = tid; i < nl; i += 256) ann[i] = ann_g[b * nl + i];
    __syncthreads();

    float regl = 0.0f, posf = 0.0f;
    int mv = -2;
    const int a = a0 + tid;
    if (a < A) {
        const float4 ab = *reinterpret_cast<const float4*>(anchors + (size_t)a * 4);
        const float aw = ab.z - ab.x, ah = ab.w - ab.y;
        const float areaA = aw * ah;
        float best = -3.0e38f; int arg = 0;
        for (int m = 0; m < M; ++m) {
            const float bx1 = ann[m*5+0], by1 = ann[m*5+1];
            const float bx2 = ann[m*5+2], by2 = ann[m*5+3];
            const float lb  = ann[m*5+4];
            float iw = fmaxf(fminf(ab.z, bx2) - fmaxf(ab.x, bx1), 0.0f);
            float ih = fmaxf(fminf(ab.w, by2) - fmaxf(ab.y, by1), 0.0f);
            float inter = iw * ih;
            float ua = fmaxf(areaA + (bx2-bx1)*(by2-by1) - inter, 1e-8f);
            float iou = inter / ua;
            iou = (lb != -1.0f) ? iou : -1.0f;
            if (iou > best) { best = iou; arg = m; }
        }
        if (best >= 0.5f) {
            mv = (int)ann[arg*5+4]; posf = 1.0f;
            const float4 rg = *reinterpret_cast<const float4*>(regr + ((size_t)b*A + a)*4);
            const float gx1 = ann[arg*5+0], gy1 = ann[arg*5+1];
            const float gx2 = ann[arg*5+2], gy2 = ann[arg*5+3];
            const float acx = ab.x + 0.5f*aw, acy = ab.y + 0.5f*ah;
            const float gwr = gx2-gx1, ghr = gy2-gy1;
            const float gcx = gx1 + 0.5f*gwr, gcy = gy1 + 0.5f*ghr;
            const float gw = fmaxf(gwr, 1.0f), gh = fmaxf(ghr, 1.0f);
            const float t0 = ((gcx-acx)/aw)/0.1f, t1 = ((gcy-acy)/ah)/0.1f;
            const float t2 = logf(gw/aw)/0.2f,    t3 = logf(gh/ah)/0.2f;
            const float d0 = fabsf(t0-rg.x), d1 = fabsf(t1-rg.y);
            const float d2 = fabsf(t2-rg.z), d3 = fabsf(t3-rg.w);
            const float th = 1.0f/9.0f, c = 0.5f/9.0f;
            regl  = (d0<=th)?4.5f*d0*d0:d0-c;  regl += (d1<=th)?4.5f*d1*d1:d1-c;
            regl += (d2<=th)?4.5f*d2*d2:d2-c;  regl += (d3<=th)?4.5f*d3*d3:d3-c;
        } else if (best < 0.4f) { mv = -1; }
    }
    smeta[tid] = mv;
    __syncthreads();

    const int span = min(CHUNK, A - a0);
    const int nv = span * KV;
    const float4* __restrict__ base =
        reinterpret_cast<const float4*>(cls + ((size_t)b*A + a0) * (KV*4));
    float acc = 0.0f;
    for (int t = tid; t < nv; t += 256) {
        const float4 c4 = base[t];
        const int la = t / KV, kbase = (t % KV) * 4;
        const int m2 = smeta[la];
        if (m2 != -2) {
            const float cv[4] = {c4.x, c4.y, c4.z, c4.w};
            #pragma unroll
            for (int j = 0; j < 4; ++j) {
                const float cc = fminf(fmaxf(cv[j], 1e-4f), 0.9999f);
                const bool t1 = (m2 == kbase + j);
                const float x = t1 ? cc : (1.0f - cc);
                const float w = t1 ? 0.25f*(1.0f-cc)*(1.0f-cc) : 0.75f*cc*cc;
                acc += w * (-__logf(x));
            }
        }
    }

    #pragma unroll
    for (int off = 32; off > 0; off >>= 1) {
        acc  += __shfl_down(acc,  off, 64);
        regl += __shfl_down(regl, off, 64);
        posf += __shfl_down(posf, off, 64);
    }
    __shared__ float wred[12];
    const int wave = tid >> 6, lane = tid & 63;
    if (lane == 0) { wred[wave] = acc; wred[4+wave] = regl; wred[8+wave] = posf; }
    __syncthreads();
    if (tid == 0) {
        const size_t o = (size_t)b * gridDim.x + blk;
        pcls[o] = wred[0]+wred[1]+wred[2]+wred[3];
        preg[o] = wred[4]+wred[5]+wred[6]+wred[7];
        ppos[o] = wred[8]+wred[9]+wred[10]+wred[11];
    }
}

__global__ __launch_bounds__(256) void finalize_kernel(
    const float* __restrict__ ann_g,    // [B,M,5]
    const float* __restrict__ pcls,
    const float* __restrict__ preg,
    const float* __restrict__ ppos,
    float* __restrict__ out,
    int B, int M, int nblk)
{
    const int tid = threadIdx.x;
    __shared__ float red[12];
    float cm = 0.0f, rm = 0.0f;          // live only in tid 0

    for (int b = 0; b < B; ++b) {
        float c = 0.0f, r = 0.0f, p = 0.0f;
        for (int i = tid; i < nblk; i += 256) {
            const size_t o = (size_t)b * nblk + i;
            c += pcls[o]; r += preg[o]; p += ppos[o];
        }
        #pragma unroll
        for (int off = 32; off > 0; off >>= 1) {
            c += __shfl_down(c, off, 64);
            r += __shfl_down(r, off, 64);
            p += __shfl_down(p, off, 64);
        }
        const int wave = tid >> 6, lane = tid & 63;
        if (lane == 0) { red[wave] = c; red[4+wave] = r; red[8+wave] = p; }
        __syncthreads();
        if (tid == 0) {
            const float cs = red[0]+red[1]+red[2]+red[3];
            const float rs = red[4]+red[5]+red[6]+red[7];
            const float ps = red[8]+red[9]+red[10]+red[11];
            bool hv = false;
            for (int m = 0; m < M; ++m)
                if (ann_g[((size_t)b * M + m) * 5 + 4] != -1.0f) { hv = true; break; }
            const float ct = hv ? cs / fmaxf(ps, 1.0f) : 0.0f;
            const float rt = (ps > 0.0f) ? rs / fmaxf(ps * 4.0f, 1.0f) : 0.0f;
            cm += ct; rm += rt;
        }
        __syncthreads();                 // red[] reused next image
    }
    if (tid == 0) { out[0] = cm / (float)B; out[1] = rm / (float)B; }
}

extern "C" void kernel_launch(void* const* d_in, const int* in_sizes, int n_in,
                              void* d_out, int out_size, void* d_ws, size_t ws_size,
                              hipStream_t stream) {
    const float* cls = (const float*)d_in[0];   // [B,A,K]
    const float* reg = (const float*)d_in[1];   // [B,A,4]
    const float* anc = (const float*)d_in[2];   // [1,A,4]
    const float* ann = (const float*)d_in[3];   // [B,M,5]

    const int A = in_sizes[2] / 4;
    const int B = in_sizes[1] / (A * 4);
    const int M = in_sizes[3] / (B * 5);
    const int K = in_sizes[0] / (B * A);
    const int nblk = (A + CHUNK - 1) / CHUNK;

    float* out = (float*)d_out;
    // workspace: three [B,nblk] partial arrays; every slot written by kernel 1.
    float* pcls = (float*)d_ws;
    float* preg = pcls + (size_t)B * nblk;
    float* ppos = preg + (size_t)B * nblk;

    dim3 grid(nblk, B);
    if (K == 80) {
        fused_kernel<20><<<grid, 256, 0, stream>>>(cls, reg, anc, ann,
                                                   pcls, preg, ppos, A, M);
    } else {
        fused_generic<<<grid, 256, 0, stream>>>(cls, reg, anc, ann,
                                                pcls, preg, ppos, A, M, K / 4);
    }
    finalize_kernel<<<1, 256, 0, stream>>>(ann, pcls, preg, ppos, out, B, M, nblk);
}